// Round 2
// baseline (212.258 us; speedup 1.0000x reference)
//
#include <hip/hip_runtime.h>
#include <stdint.h>

// MultiHeadAttention w/ RoPE, causal. B=2, T=2048, C=1024, H=16, Dh=64.
// Round 14: attn load-balance + latency pipeline.
//  (a) causal pairing: grid (16,32); each block does q-tiles x and 31-x ->
//      uniform 33 KV-iters/block (fixes linear-dispatch pathology where CU c
//      got 4 blocks of identical trip count x=c%32, critical path 128 iters).
//  (b) T14 async-STAGE: K/V loads for tile kc+1 issued after compute barrier
//      of tile kc; latency hides under QK/softmax/PV.
//  Keeps Round 13: DPP row_ror reductions (VALU pipe), exp2-domain softmax,
//  per-wave-private LDS transpose slices without barriers, native RoPE trig.

typedef float  f32x4  __attribute__((ext_vector_type(4)));
typedef __bf16 bf16x8 __attribute__((ext_vector_type(8)));

#define GLDS16(gp, lp)                                                         \
  __builtin_amdgcn_global_load_lds(                                            \
      (const __attribute__((address_space(1))) void*)(gp),                     \
      (__attribute__((address_space(3))) void*)(lp), 16, 0, 0)

static __device__ __forceinline__ f32x4 zero4() {
  f32x4 z = {0.f, 0.f, 0.f, 0.f};
  return z;
}

static __device__ __forceinline__ bf16x8 cvt8(const float* __restrict__ p) {
  f32x4 u = *(const f32x4*)p;
  f32x4 v = *(const f32x4*)(p + 4);
  bf16x8 o;
#pragma unroll
  for (int j = 0; j < 4; ++j) o[j] = (__bf16)u[j];
#pragma unroll
  for (int j = 0; j < 4; ++j) o[4 + j] = (__bf16)v[j];
  return o;
}

// DPP row_ror<N> within 16-lane rows: VALU-pipe lane rotation.
// Rotation-based reduce over {1,2,4,8} covers all 16 lanes exactly once.
template <int N>
static __device__ __forceinline__ float ror16(float x) {
  int v = __builtin_amdgcn_update_dpp(0, __float_as_int(x),
                                      0x120 | N, 0xF, 0xF, true);
  return __int_as_float(v);
}

static __device__ __forceinline__ float redmax16(float x) {
  x = fmaxf(x, ror16<1>(x));
  x = fmaxf(x, ror16<2>(x));
  x = fmaxf(x, ror16<4>(x));
  x = fmaxf(x, ror16<8>(x));
  return x;
}

static __device__ __forceinline__ float redsum16(float x) {
  x += ror16<1>(x);
  x += ror16<2>(x);
  x += ror16<4>(x);
  x += ror16<8>(x);
  return x;
}

// ---------------------------------------------------------------------------
// Prepass: x (4M f32) -> xb bf16; Wq/Wk/Wv/Wo (1M f32 each) -> Wb bf16[4][1M].
// ---------------------------------------------------------------------------
__global__ __launch_bounds__(256) void prep(
    const float* __restrict__ x,
    const float* __restrict__ Wq, const float* __restrict__ Wk,
    const float* __restrict__ Wv, const float* __restrict__ Wo,
    __bf16* __restrict__ xb, __bf16* __restrict__ Wb)
{
  size_t g = ((size_t)blockIdx.x * 256 + threadIdx.x) * 8;
  if (g < (size_t)4194304) {
    *(bf16x8*)&xb[g] = cvt8(x + g);
  } else {
    size_t j = g - 4194304;
    int w = (int)(j >> 20);
    size_t off = j & 1048575;
    const float* src = (w == 0) ? Wq : (w == 1) ? Wk : (w == 2) ? Wv : Wo;
    *(bf16x8*)&Wb[(size_t)w * 1048576 + off] = cvt8(src + off);
  }
}

// ---------------------------------------------------------------------------
// QKV GEMM (bf16 x bf16): C[m][n] = sum_k xb[m][k]*W[n][k]. 128x128, BK=32,
// GLDS16 staging. z<2: RoPE fused, plain store Qp/Kp. z=2: V^T [bh][d][t].
// All global stores: full-line b128 via per-wave LDS transpose (no barriers
// needed: each wave's Es slice is private, same-wave ds ops are ordered).
// ---------------------------------------------------------------------------
__global__ __launch_bounds__(256) void gemm_qkv(
    const __bf16* __restrict__ xb, const __bf16* __restrict__ Wb,
    __bf16* __restrict__ Qp, __bf16* __restrict__ Kp, __bf16* __restrict__ Vt)
{
  __shared__ __bf16 As[128 * 32];
  __shared__ __bf16 Bs[128 * 32];
  __shared__ __bf16 Es[4 * 16 * 72];   // per-wave 16x72 transpose tile

  const int tid  = threadIdx.x;
  const int lane = tid & 63;
  const int wid  = tid >> 6;
  const int quad = lane >> 4;
  const int l16  = lane & 15;
  const int wm   = (wid >> 1) * 64;
  const int wn   = (wid & 1) * 64;

  const int lin = blockIdx.x;           // 768 blocks
  const int n0  = (lin & 7) * 128;
  const int r2  = lin >> 3;
  const int z   = r2 % 3;
  const int m0  = (r2 / 3) * 128;
  const __bf16* Bt = Wb + (size_t)z * 1048576;

  const int r0 = tid >> 2, c0 = tid & 3;
  const int r1 = (tid + 256) >> 2;

  f32x4 acc[4][4];
  for (int i = 0; i < 4; ++i)
    for (int j = 0; j < 4; ++j) acc[i][j] = zero4();

  for (int k0 = 0; k0 < 1024; k0 += 32) {
    __syncthreads();
    GLDS16(xb + (size_t)(m0 + r0) * 1024 + k0 + c0 * 8, &As[(size_t)tid * 8]);
    GLDS16(xb + (size_t)(m0 + r1) * 1024 + k0 + c0 * 8, &As[(size_t)(tid + 256) * 8]);
    GLDS16(Bt + (size_t)(n0 + r0) * 1024 + k0 + c0 * 8, &Bs[(size_t)tid * 8]);
    GLDS16(Bt + (size_t)(n0 + r1) * 1024 + k0 + c0 * 8, &Bs[(size_t)(tid + 256) * 8]);
    __syncthreads();

    bf16x8 af[4], bfr[4];
    for (int i = 0; i < 4; ++i)
      af[i] = *(const bf16x8*)&As[(wm + i * 16 + l16) * 32 + quad * 8];
    for (int i = 0; i < 4; ++i)
      bfr[i] = *(const bf16x8*)&Bs[(wn + i * 16 + l16) * 32 + quad * 8];
    for (int mt = 0; mt < 4; ++mt)
      for (int nt = 0; nt < 4; ++nt)
        acc[mt][nt] = __builtin_amdgcn_mfma_f32_16x16x32_bf16(
            af[mt], bfr[nt], acc[mt][nt], 0, 0, 0);
  }

  // D layout: row = 4*quad + reg, col = l16 per 16x16 subtile.
  const int h = (n0 + wn) >> 6;
  __bf16* es = &Es[wid * 1152];        // 16 x 72, per-wave private
  const int rl = lane >> 3, ch = lane & 7;

  if (z < 2) {
    // fused RoPE (native trig: |err| ~2e-4 << bf16 quantization)
    const float c0f = -13.287712379549449f / 32.0f;  // -log2(10000)/32
    const float f0 = exp2f((float)l16 * c0f);
    const float f1 = exp2f((float)(16 + l16) * c0f);
    for (int mt = 0; mt < 4; ++mt)
      for (int r = 0; r < 4; ++r) {
        int gm = m0 + wm + mt * 16 + 4 * quad + r;
        float t = (float)(gm & 2047);
        for (int nt = 0; nt < 2; ++nt) {
          float ang = t * (nt ? f1 : f0);
          float cv = __cosf(ang), sv = __sinf(ang);
          float lo = acc[mt][nt][r], hi = acc[mt][nt + 2][r];
          acc[mt][nt][r]     = lo * cv - hi * sv;
          acc[mt][nt + 2][r] = hi * cv + lo * sv;
        }
      }
    __bf16* dst = (z == 0) ? Qp : Kp;
    for (int mt = 0; mt < 4; ++mt) {
      for (int nt = 0; nt < 4; ++nt)
        for (int r = 0; r < 4; ++r)
          es[(4 * quad + r) * 72 + nt * 16 + l16] = (__bf16)acc[mt][nt][r];
      size_t g0 = (size_t)(m0 + wm + mt * 16 + rl) * 1024 + n0 + wn + ch * 8;
      *(bf16x8*)&dst[g0]            = *(const bf16x8*)&es[rl * 72 + ch * 8];
      *(bf16x8*)&dst[g0 + 8 * 1024] = *(const bf16x8*)&es[(rl + 8) * 72 + ch * 8];
    }
  } else {
    // V^T: Vt[(b*16+h)*64 + d][t]
    const int b = m0 >> 11;
    const size_t hb = (size_t)(b * 16 + h) * 64;
    const int tt = (m0 + wm) & 2047;
    for (int nt = 0; nt < 4; ++nt) {
      for (int mt = 0; mt < 4; ++mt)
        for (int r = 0; r < 4; ++r)
          es[l16 * 72 + mt * 16 + 4 * quad + r] = (__bf16)acc[mt][nt][r];
      size_t g0 = (hb + nt * 16 + rl) * 2048 + tt + ch * 8;
      *(bf16x8*)&Vt[g0]                     = *(const bf16x8*)&es[rl * 72 + ch * 8];
      *(bf16x8*)&Vt[g0 + (size_t)8 * 2048]  = *(const bf16x8*)&es[(rl + 8) * 72 + ch * 8];
    }
  }
}

// ---------------------------------------------------------------------------
// Flash attention (causal). Q/K plain [b*t][1024] (head at col h*64),
// V^T [bh][d][t]. AO in-place into QA. Full-line output stores via Ps.
// Causal pairing: block x handles q-tiles x and 31-x (uniform 33 KV-iters).
// K/V loads for tile kc+1 issued during compute of tile kc (T14 split).
// ---------------------------------------------------------------------------
__global__ __launch_bounds__(256) void attn_fwd(
    __bf16* QA, const __bf16* __restrict__ Kp,
    const __bf16* __restrict__ Vt)
{
  __shared__ __bf16 Ks[64 * 72];   // [kpos][d]
  __shared__ __bf16 Vs[64 * 72];   // [d][kpos]
  __shared__ __bf16 Ps[64 * 72];   // [q][kpos] / output transpose buffer

  const int tid  = threadIdx.x;
  const int lane = tid & 63, wid = tid >> 6;
  const int quad = lane >> 4, l16 = lane & 15;
  const int bh = blockIdx.y;
  const int b = bh >> 4, h = bh & 15;

  const size_t rowb = (size_t)b * 2048;
  const __bf16* Vb = Vt + (size_t)bh * 64 * 2048;

  const int sr0 = tid >> 3, sc0 = tid & 7;
  const int sr1 = (tid + 256) >> 3;

  // 0.125 (1/sqrt(64)) folded with log2(e): softmax in base-2 domain (exact)
  const float SC = 0.125f * 1.44269504088896340736f;

  for (int pass = 0; pass < 2; ++pass) {
    const int qb = pass ? (31 - (int)blockIdx.x) : (int)blockIdx.x;
    const int q0 = qb * 64;

    bf16x8 qa[2];
    for (int ks = 0; ks < 2; ++ks)
      qa[ks] = *(const bf16x8*)
          &QA[(rowb + q0 + wid * 16 + l16) * 1024 + h * 64 + ks * 32 + quad * 8];

    f32x4 oacc[4];
    for (int i = 0; i < 4; ++i) oacc[i] = zero4();
    float m_i[4], l_i[4];
    for (int r = 0; r < 4; ++r) { m_i[r] = -1e30f; l_i[r] = 0.f; }

    const int kcmax = qb;

    // prologue: prefetch KV tile 0
    bf16x8 k0v = *(const bf16x8*)&Kp[(rowb + sr0) * 1024 + h * 64 + sc0 * 8];
    bf16x8 k1v = *(const bf16x8*)&Kp[(rowb + sr1) * 1024 + h * 64 + sc0 * 8];
    bf16x8 v0v = *(const bf16x8*)&Vb[(size_t)sr0 * 2048 + sc0 * 8];
    bf16x8 v1v = *(const bf16x8*)&Vb[(size_t)sr1 * 2048 + sc0 * 8];

    for (int kc = 0; kc <= kcmax; ++kc) {
      __syncthreads();   // previous tile's LDS reads complete (all waves)
      *(bf16x8*)&Ks[sr0 * 72 + sc0 * 8] = k0v;
      *(bf16x8*)&Ks[sr1 * 72 + sc0 * 8] = k1v;
      *(bf16x8*)&Vs[sr0 * 72 + sc0 * 8] = v0v;
      *(bf16x8*)&Vs[sr1 * 72 + sc0 * 8] = v1v;
      __syncthreads();

      // T14: issue next tile's loads now; latency hides under compute below.
      if (kc < kcmax) {
        const int kn = kc + 1;
        k0v = *(const bf16x8*)&Kp[(rowb + kn * 64 + sr0) * 1024 + h * 64 + sc0 * 8];
        k1v = *(const bf16x8*)&Kp[(rowb + kn * 64 + sr1) * 1024 + h * 64 + sc0 * 8];
        v0v = *(const bf16x8*)&Vb[(size_t)sr0 * 2048 + kn * 64 + sc0 * 8];
        v1v = *(const bf16x8*)&Vb[(size_t)sr1 * 2048 + kn * 64 + sc0 * 8];
      }

      f32x4 sacc[4];
      for (int i = 0; i < 4; ++i) sacc[i] = zero4();
      for (int ks = 0; ks < 2; ++ks) {
        bf16x8 qf = qa[ks];
        for (int nt = 0; nt < 4; ++nt) {
          bf16x8 kf = *(const bf16x8*)
              &Ks[(nt * 16 + l16) * 72 + ks * 32 + quad * 8];
          sacc[nt] = __builtin_amdgcn_mfma_f32_16x16x32_bf16(
              qf, kf, sacc[nt], 0, 0, 0);
        }
      }

      const bool diag = (kc == kcmax);
      float rmax[4] = {-1e30f, -1e30f, -1e30f, -1e30f};
      for (int nt = 0; nt < 4; ++nt)
        for (int r = 0; r < 4; ++r) {
          float s = sacc[nt][r] * SC;
          if (diag) {
            int i = wid * 16 + 4 * quad + r;
            int j = nt * 16 + l16;
            if (j > i) s = -1e30f;
          }
          sacc[nt][r] = s;
          rmax[r] = fmaxf(rmax[r], s);
        }
      for (int r = 0; r < 4; ++r)
        rmax[r] = redmax16(rmax[r]);          // DPP, VALU pipe

      float alpha[4], rsum[4];
      for (int r = 0; r < 4; ++r) {
        float nm = fmaxf(m_i[r], rmax[r]);
        alpha[r] = __builtin_amdgcn_exp2f(m_i[r] - nm);
        m_i[r] = nm;
        rsum[r] = 0.f;
      }
      for (int nt = 0; nt < 4; ++nt)
        for (int r = 0; r < 4; ++r) {
          float p = __builtin_amdgcn_exp2f(sacc[nt][r] - m_i[r]);
          rsum[r] += p;
          Ps[(wid * 16 + 4 * quad + r) * 72 + nt * 16 + l16] = (__bf16)p;
        }
      // no barrier: Ps rows [wid*16, wid*16+16) are written and read only by
      // this wave; same-wave LDS ops complete in order.
      for (int r = 0; r < 4; ++r) {
        rsum[r] = redsum16(rsum[r]);          // DPP, VALU pipe
        l_i[r] = l_i[r] * alpha[r] + rsum[r];
        for (int nt = 0; nt < 4; ++nt) oacc[nt][r] *= alpha[r];
      }

      for (int ks = 0; ks < 2; ++ks) {
        bf16x8 pf = *(const bf16x8*)
            &Ps[(wid * 16 + l16) * 72 + ks * 32 + quad * 8];
        for (int nt = 0; nt < 4; ++nt) {
          bf16x8 vf = *(const bf16x8*)
              &Vs[(nt * 16 + l16) * 72 + ks * 32 + quad * 8];
          oacc[nt] = __builtin_amdgcn_mfma_f32_16x16x32_bf16(
              pf, vf, oacc[nt], 0, 0, 0);
        }
      }
    }

    // coalesced output: oacc -> Ps -> full-line b128 stores.
    for (int r = 0; r < 4; ++r) {
      float inv = 1.f / l_i[r];
      for (int nt = 0; nt < 4; ++nt)
        Ps[(wid * 16 + 4 * quad + r) * 72 + nt * 16 + l16] =
            (__bf16)(oacc[nt][r] * inv);
    }
    __syncthreads();
    {
      int row = tid >> 3, ch = tid & 7;        // 32 rows x 8 chunks
      size_t g0 = (rowb + q0 + row) * 1024 + h * 64 + ch * 8;
      *(bf16x8*)&QA[g0]                   = *(const bf16x8*)&Ps[row * 72 + ch * 8];
      *(bf16x8*)&QA[g0 + (size_t)32 * 1024] =
          *(const bf16x8*)&Ps[(row + 32) * 72 + ch * 8];
    }
    __syncthreads();   // isolate passes: Ps reads done before pass-2 writes
  }
}

// ---------------------------------------------------------------------------
// Output GEMM: out[m][n] = sum_k AO[m][k]*Wo[n][k], fp32 out, full-line f32x4.
// ---------------------------------------------------------------------------
__global__ __launch_bounds__(256) void gemm_out(
    const __bf16* __restrict__ AO, const __bf16* __restrict__ Wob,
    float* __restrict__ Of)
{
  __shared__ __bf16 As[128 * 32];
  __shared__ __bf16 Bs[128 * 32];
  __shared__ float  EsF[4 * 16 * 68];

  const int tid  = threadIdx.x;
  const int lane = tid & 63;
  const int wid  = tid >> 6;
  const int quad = lane >> 4;
  const int l16  = lane & 15;
  const int wm   = (wid >> 1) * 64;
  const int wn   = (wid & 1) * 64;
  const int lin = blockIdx.x;           // 256 blocks
  const int n0  = (lin & 7) * 128;
  const int m0  = (lin >> 3) * 128;

  const int r0 = tid >> 2, c0 = tid & 3;
  const int r1 = (tid + 256) >> 2;

  f32x4 acc[4][4];
  for (int i = 0; i < 4; ++i)
    for (int j = 0; j < 4; ++j) acc[i][j] = zero4();

  for (int k0 = 0; k0 < 1024; k0 += 32) {
    __syncthreads();
    GLDS16(AO  + (size_t)(m0 + r0) * 1024 + k0 + c0 * 8, &As[(size_t)tid * 8]);
    GLDS16(AO  + (size_t)(m0 + r1) * 1024 + k0 + c0 * 8, &As[(size_t)(tid + 256) * 8]);
    GLDS16(Wob + (size_t)(n0 + r0) * 1024 + k0 + c0 * 8, &Bs[(size_t)tid * 8]);
    GLDS16(Wob + (size_t)(n0 + r1) * 1024 + k0 + c0 * 8, &Bs[(size_t)(tid + 256) * 8]);
    __syncthreads();

    bf16x8 af[4], bfr[4];
    for (int i = 0; i < 4; ++i)
      af[i] = *(const bf16x8*)&As[(wm + i * 16 + l16) * 32 + quad * 8];
    for (int i = 0; i < 4; ++i)
      bfr[i] = *(const bf16x8*)&Bs[(wn + i * 16 + l16) * 32 + quad * 8];
    for (int mt = 0; mt < 4; ++mt)
      for (int nt = 0; nt < 4; ++nt)
        acc[mt][nt] = __builtin_amdgcn_mfma_f32_16x16x32_bf16(
            af[mt], bfr[nt], acc[mt][nt], 0, 0, 0);
  }

  float* es = &EsF[wid * 1088];         // 16 x 68 f32, per-wave private
  const int rl = lane >> 4, ch = lane & 15;
  for (int mt = 0; mt < 4; ++mt) {
    for (int nt = 0; nt < 4; ++nt)
      for (int r = 0; r < 4; ++r)
        es[(4 * quad + r) * 68 + nt * 16 + l16] = acc[mt][nt][r];
    size_t g0 = (size_t)(m0 + wm + mt * 16 + rl) * 1024 + n0 + wn + ch * 4;
    *(f32x4*)&Of[g0]             = *(const f32x4*)&es[rl * 68 + ch * 4];
    *(f32x4*)&Of[g0 + 4 * 1024]  = *(const f32x4*)&es[(rl + 4) * 68 + ch * 4];
    *(f32x4*)&Of[g0 + 8 * 1024]  = *(const f32x4*)&es[(rl + 8) * 68 + ch * 4];
    *(f32x4*)&Of[g0 + 12 * 1024] = *(const f32x4*)&es[(rl + 12) * 68 + ch * 4];
  }
}

// copy 8 bf16/lane
__global__ __launch_bounds__(256) void copy_bf16x8(
    const __bf16* __restrict__ src, __bf16* __restrict__ dst)
{
  size_t i = ((size_t)blockIdx.x * 256 + threadIdx.x) * 8;
  *(bf16x8*)&dst[i] = *(const bf16x8*)&src[i];
}

// ---------------------------------------------------------------------------
extern "C" void kernel_launch(void* const* d_in, const int* in_sizes, int n_in,
                              void* d_out, int out_size, void* d_ws, size_t ws_size,
                              hipStream_t stream) {
  const float* x  = (const float*)d_in[0];
  const float* Wq = (const float*)d_in[1];
  const float* Wk = (const float*)d_in[2];
  const float* Wv = (const float*)d_in[3];
  const float* Wo = (const float*)d_in[4];
  float* out = (float*)d_out;

  const size_t NELT = (size_t)4194304;             // 4M elems (8 MiB bf16)
  __bf16* Qp = (__bf16*)d_ws;        // plain Q, becomes AO in-place
  __bf16* Kp = Qp + NELT;            // plain K, later holds Wo bf16
  __bf16* Vt = Kp + NELT;            // V^T [bh][d][t]
  __bf16* xb = (__bf16*)d_out;       // d_out[0:8MB) scratch: x bf16
  __bf16* Wb = xb + NELT;            // d_out[8:16MB): W* bf16

  prep<<<dim3(4096), 256, 0, stream>>>(x, Wq, Wk, Wv, Wo, xb, Wb);
  gemm_qkv<<<dim3(768), 256, 0, stream>>>(xb, Wb, Qp, Kp, Vt);
  attn_fwd<<<dim3(16, 32), 256, 0, stream>>>(Qp, Kp, Vt);
  copy_bf16x8<<<dim3(512), 256, 0, stream>>>(Wb + 3 * NELT / 4, Kp);
  gemm_out<<<dim3(256), 256, 0, stream>>>(Qp, Kp, out);
}

// Round 3
// 212.204 us; speedup vs baseline: 1.0003x; 1.0003x over previous
//
#include <hip/hip_runtime.h>
#include <stdint.h>

// MultiHeadAttention w/ RoPE, causal. B=2, T=2048, C=1024, H=16, Dh=64.
// Round 15: attn L2 locality + VALU trim.
//  (a) XCD-aware swizzle: 1-D grid 512, Lp=(L&7)*64+(L>>3) -> all 16 blocks
//      of a head land on one XCD; KV panel (512KB/head, 4 heads = 2MB) stays
//      in that XCD's 4MB L2. R2 counters showed 120MB HBM fetch of a 16MB
//      working set (8x re-fetch) = the latency source.
//  (b) softmax scale 0.125*log2e folded into Q's RoPE rotation in gemm_qkv
//      (cv,sv *= SC for z==0): removes 16 v_mul per wave-iter in attn.
//  (c) s_setprio(1) around attn MFMA clusters (T5).
//  Keeps R13/R14: DPP reductions, exp2-domain softmax, causal pairing,
//  T14 prefetch, per-wave-private LDS epilogue slices, native RoPE trig.

typedef float  f32x4  __attribute__((ext_vector_type(4)));
typedef __bf16 bf16x8 __attribute__((ext_vector_type(8)));

#define GLDS16(gp, lp)                                                         \
  __builtin_amdgcn_global_load_lds(                                            \
      (const __attribute__((address_space(1))) void*)(gp),                     \
      (__attribute__((address_space(3))) void*)(lp), 16, 0, 0)

static __device__ __forceinline__ f32x4 zero4() {
  f32x4 z = {0.f, 0.f, 0.f, 0.f};
  return z;
}

static __device__ __forceinline__ bf16x8 cvt8(const float* __restrict__ p) {
  f32x4 u = *(const f32x4*)p;
  f32x4 v = *(const f32x4*)(p + 4);
  bf16x8 o;
#pragma unroll
  for (int j = 0; j < 4; ++j) o[j] = (__bf16)u[j];
#pragma unroll
  for (int j = 0; j < 4; ++j) o[4 + j] = (__bf16)v[j];
  return o;
}

// DPP row_ror<N> within 16-lane rows: VALU-pipe lane rotation.
template <int N>
static __device__ __forceinline__ float ror16(float x) {
  int v = __builtin_amdgcn_update_dpp(0, __float_as_int(x),
                                      0x120 | N, 0xF, 0xF, true);
  return __int_as_float(v);
}

static __device__ __forceinline__ float redmax16(float x) {
  x = fmaxf(x, ror16<1>(x));
  x = fmaxf(x, ror16<2>(x));
  x = fmaxf(x, ror16<4>(x));
  x = fmaxf(x, ror16<8>(x));
  return x;
}

static __device__ __forceinline__ float redsum16(float x) {
  x += ror16<1>(x);
  x += ror16<2>(x);
  x += ror16<4>(x);
  x += ror16<8>(x);
  return x;
}

// ---------------------------------------------------------------------------
// Prepass: x (4M f32) -> xb bf16; Wq/Wk/Wv/Wo (1M f32 each) -> Wb bf16[4][1M].
// ---------------------------------------------------------------------------
__global__ __launch_bounds__(256) void prep(
    const float* __restrict__ x,
    const float* __restrict__ Wq, const float* __restrict__ Wk,
    const float* __restrict__ Wv, const float* __restrict__ Wo,
    __bf16* __restrict__ xb, __bf16* __restrict__ Wb)
{
  size_t g = ((size_t)blockIdx.x * 256 + threadIdx.x) * 8;
  if (g < (size_t)4194304) {
    *(bf16x8*)&xb[g] = cvt8(x + g);
  } else {
    size_t j = g - 4194304;
    int w = (int)(j >> 20);
    size_t off = j & 1048575;
    const float* src = (w == 0) ? Wq : (w == 1) ? Wk : (w == 2) ? Wv : Wo;
    *(bf16x8*)&Wb[(size_t)w * 1048576 + off] = cvt8(src + off);
  }
}

// ---------------------------------------------------------------------------
// QKV GEMM (bf16 x bf16): C[m][n] = sum_k xb[m][k]*W[n][k]. 128x128, BK=32,
// GLDS16 staging. z<2: RoPE fused (Q pre-scaled by 0.125*log2e), plain store
// Qp/Kp. z=2: V^T [bh][d][t]. Full-line b128 stores via per-wave LDS tiles.
// ---------------------------------------------------------------------------
__global__ __launch_bounds__(256) void gemm_qkv(
    const __bf16* __restrict__ xb, const __bf16* __restrict__ Wb,
    __bf16* __restrict__ Qp, __bf16* __restrict__ Kp, __bf16* __restrict__ Vt)
{
  __shared__ __bf16 As[128 * 32];
  __shared__ __bf16 Bs[128 * 32];
  __shared__ __bf16 Es[4 * 16 * 72];   // per-wave 16x72 transpose tile

  const int tid  = threadIdx.x;
  const int lane = tid & 63;
  const int wid  = tid >> 6;
  const int quad = lane >> 4;
  const int l16  = lane & 15;
  const int wm   = (wid >> 1) * 64;
  const int wn   = (wid & 1) * 64;

  const int lin = blockIdx.x;           // 768 blocks
  const int n0  = (lin & 7) * 128;
  const int r2  = lin >> 3;
  const int z   = r2 % 3;
  const int m0  = (r2 / 3) * 128;
  const __bf16* Bt = Wb + (size_t)z * 1048576;

  const int r0 = tid >> 2, c0 = tid & 3;
  const int r1 = (tid + 256) >> 2;

  f32x4 acc[4][4];
  for (int i = 0; i < 4; ++i)
    for (int j = 0; j < 4; ++j) acc[i][j] = zero4();

  for (int k0 = 0; k0 < 1024; k0 += 32) {
    __syncthreads();
    GLDS16(xb + (size_t)(m0 + r0) * 1024 + k0 + c0 * 8, &As[(size_t)tid * 8]);
    GLDS16(xb + (size_t)(m0 + r1) * 1024 + k0 + c0 * 8, &As[(size_t)(tid + 256) * 8]);
    GLDS16(Bt + (size_t)(n0 + r0) * 1024 + k0 + c0 * 8, &Bs[(size_t)tid * 8]);
    GLDS16(Bt + (size_t)(n0 + r1) * 1024 + k0 + c0 * 8, &Bs[(size_t)(tid + 256) * 8]);
    __syncthreads();

    bf16x8 af[4], bfr[4];
    for (int i = 0; i < 4; ++i)
      af[i] = *(const bf16x8*)&As[(wm + i * 16 + l16) * 32 + quad * 8];
    for (int i = 0; i < 4; ++i)
      bfr[i] = *(const bf16x8*)&Bs[(wn + i * 16 + l16) * 32 + quad * 8];
    for (int mt = 0; mt < 4; ++mt)
      for (int nt = 0; nt < 4; ++nt)
        acc[mt][nt] = __builtin_amdgcn_mfma_f32_16x16x32_bf16(
            af[mt], bfr[nt], acc[mt][nt], 0, 0, 0);
  }

  // D layout: row = 4*quad + reg, col = l16 per 16x16 subtile.
  const int h = (n0 + wn) >> 6;
  __bf16* es = &Es[wid * 1152];        // 16 x 72, per-wave private
  const int rl = lane >> 3, ch = lane & 7;

  if (z < 2) {
    // fused RoPE; for Q (z==0) fold softmax scale 0.125*log2(e) into cv/sv.
    const float c0f = -13.287712379549449f / 32.0f;  // -log2(10000)/32
    const float f0 = exp2f((float)l16 * c0f);
    const float f1 = exp2f((float)(16 + l16) * c0f);
    const float SC = (z == 0) ? 0.125f * 1.44269504088896340736f : 1.0f;
    for (int mt = 0; mt < 4; ++mt)
      for (int r = 0; r < 4; ++r) {
        int gm = m0 + wm + mt * 16 + 4 * quad + r;
        float t = (float)(gm & 2047);
        for (int nt = 0; nt < 2; ++nt) {
          float ang = t * (nt ? f1 : f0);
          float cv = __cosf(ang) * SC, sv = __sinf(ang) * SC;
          float lo = acc[mt][nt][r], hi = acc[mt][nt + 2][r];
          acc[mt][nt][r]     = lo * cv - hi * sv;
          acc[mt][nt + 2][r] = hi * cv + lo * sv;
        }
      }
    __bf16* dst = (z == 0) ? Qp : Kp;
    for (int mt = 0; mt < 4; ++mt) {
      for (int nt = 0; nt < 4; ++nt)
        for (int r = 0; r < 4; ++r)
          es[(4 * quad + r) * 72 + nt * 16 + l16] = (__bf16)acc[mt][nt][r];
      size_t g0 = (size_t)(m0 + wm + mt * 16 + rl) * 1024 + n0 + wn + ch * 8;
      *(bf16x8*)&dst[g0]            = *(const bf16x8*)&es[rl * 72 + ch * 8];
      *(bf16x8*)&dst[g0 + 8 * 1024] = *(const bf16x8*)&es[(rl + 8) * 72 + ch * 8];
    }
  } else {
    // V^T: Vt[(b*16+h)*64 + d][t]
    const int b = m0 >> 11;
    const size_t hb = (size_t)(b * 16 + h) * 64;
    const int tt = (m0 + wm) & 2047;
    for (int nt = 0; nt < 4; ++nt) {
      for (int mt = 0; mt < 4; ++mt)
        for (int r = 0; r < 4; ++r)
          es[l16 * 72 + mt * 16 + 4 * quad + r] = (__bf16)acc[mt][nt][r];
      size_t g0 = (hb + nt * 16 + rl) * 2048 + tt + ch * 8;
      *(bf16x8*)&Vt[g0]                     = *(const bf16x8*)&es[rl * 72 + ch * 8];
      *(bf16x8*)&Vt[g0 + (size_t)8 * 2048]  = *(const bf16x8*)&es[(rl + 8) * 72 + ch * 8];
    }
  }
}

// ---------------------------------------------------------------------------
// Flash attention (causal). Q/K plain [b*t][1024] (head at col h*64),
// V^T [bh][d][t]. AO in-place into QA. Full-line output stores via Ps.
// Grid: 1-D 512, XCD-swizzled so each head's 16 blocks share one XCD's L2.
// Causal pairing: q-tiles xq and 31-xq (uniform 33 KV-iters). T14 prefetch.
// Q comes pre-scaled by 0.125*log2e (folded into gemm_qkv's RoPE).
// ---------------------------------------------------------------------------
__global__ __launch_bounds__(256) void attn_fwd(
    __bf16* QA, const __bf16* __restrict__ Kp,
    const __bf16* __restrict__ Vt)
{
  __shared__ __bf16 Ks[64 * 72];   // [kpos][d]
  __shared__ __bf16 Vs[64 * 72];   // [d][kpos]
  __shared__ __bf16 Ps[64 * 72];   // [q][kpos] / output transpose buffer

  const int tid  = threadIdx.x;
  const int lane = tid & 63, wid = tid >> 6;
  const int quad = lane >> 4, l16 = lane & 15;

  // XCD-aware decode: all blocks of one bh share linearID%8 -> one XCD.
  const int L  = blockIdx.x;                 // 0..511
  const int Lp = (L & 7) * 64 + (L >> 3);
  const int bh = Lp >> 4;                    // 4 heads per XCD
  const int xq = Lp & 15;                    // pair index 0..15
  const int b = bh >> 4, h = bh & 15;

  const size_t rowb = (size_t)b * 2048;
  const __bf16* Vb = Vt + (size_t)bh * 64 * 2048;

  const int sr0 = tid >> 3, sc0 = tid & 7;
  const int sr1 = (tid + 256) >> 3;

  for (int pass = 0; pass < 2; ++pass) {
    const int qb = pass ? (31 - xq) : xq;
    const int q0 = qb * 64;

    bf16x8 qa[2];
    for (int ks = 0; ks < 2; ++ks)
      qa[ks] = *(const bf16x8*)
          &QA[(rowb + q0 + wid * 16 + l16) * 1024 + h * 64 + ks * 32 + quad * 8];

    f32x4 oacc[4];
    for (int i = 0; i < 4; ++i) oacc[i] = zero4();
    float m_i[4], l_i[4];
    for (int r = 0; r < 4; ++r) { m_i[r] = -1e30f; l_i[r] = 0.f; }

    const int kcmax = qb;

    // prologue: prefetch KV tile 0
    bf16x8 k0v = *(const bf16x8*)&Kp[(rowb + sr0) * 1024 + h * 64 + sc0 * 8];
    bf16x8 k1v = *(const bf16x8*)&Kp[(rowb + sr1) * 1024 + h * 64 + sc0 * 8];
    bf16x8 v0v = *(const bf16x8*)&Vb[(size_t)sr0 * 2048 + sc0 * 8];
    bf16x8 v1v = *(const bf16x8*)&Vb[(size_t)sr1 * 2048 + sc0 * 8];

    for (int kc = 0; kc <= kcmax; ++kc) {
      __syncthreads();   // previous tile's LDS reads complete (all waves)
      *(bf16x8*)&Ks[sr0 * 72 + sc0 * 8] = k0v;
      *(bf16x8*)&Ks[sr1 * 72 + sc0 * 8] = k1v;
      *(bf16x8*)&Vs[sr0 * 72 + sc0 * 8] = v0v;
      *(bf16x8*)&Vs[sr1 * 72 + sc0 * 8] = v1v;
      __syncthreads();

      // T14: issue next tile's loads now; latency hides under compute below.
      if (kc < kcmax) {
        const int kn = kc + 1;
        k0v = *(const bf16x8*)&Kp[(rowb + kn * 64 + sr0) * 1024 + h * 64 + sc0 * 8];
        k1v = *(const bf16x8*)&Kp[(rowb + kn * 64 + sr1) * 1024 + h * 64 + sc0 * 8];
        v0v = *(const bf16x8*)&Vb[(size_t)sr0 * 2048 + kn * 64 + sc0 * 8];
        v1v = *(const bf16x8*)&Vb[(size_t)sr1 * 2048 + kn * 64 + sc0 * 8];
      }

      f32x4 sacc[4];
      for (int i = 0; i < 4; ++i) sacc[i] = zero4();
      __builtin_amdgcn_s_setprio(1);
      for (int ks = 0; ks < 2; ++ks) {
        bf16x8 qf = qa[ks];
        for (int nt = 0; nt < 4; ++nt) {
          bf16x8 kf = *(const bf16x8*)
              &Ks[(nt * 16 + l16) * 72 + ks * 32 + quad * 8];
          sacc[nt] = __builtin_amdgcn_mfma_f32_16x16x32_bf16(
              qf, kf, sacc[nt], 0, 0, 0);
        }
      }
      __builtin_amdgcn_s_setprio(0);

      const bool diag = (kc == kcmax);
      float rmax[4] = {-1e30f, -1e30f, -1e30f, -1e30f};
      for (int nt = 0; nt < 4; ++nt)
        for (int r = 0; r < 4; ++r) {
          float s = sacc[nt][r];          // pre-scaled via Q
          if (diag) {
            int i = wid * 16 + 4 * quad + r;
            int j = nt * 16 + l16;
            if (j > i) s = -1e30f;
          }
          sacc[nt][r] = s;
          rmax[r] = fmaxf(rmax[r], s);
        }
      for (int r = 0; r < 4; ++r)
        rmax[r] = redmax16(rmax[r]);          // DPP, VALU pipe

      float alpha[4], rsum[4];
      for (int r = 0; r < 4; ++r) {
        float nm = fmaxf(m_i[r], rmax[r]);
        alpha[r] = __builtin_amdgcn_exp2f(m_i[r] - nm);
        m_i[r] = nm;
        rsum[r] = 0.f;
      }
      for (int nt = 0; nt < 4; ++nt)
        for (int r = 0; r < 4; ++r) {
          float p = __builtin_amdgcn_exp2f(sacc[nt][r] - m_i[r]);
          rsum[r] += p;
          Ps[(wid * 16 + 4 * quad + r) * 72 + nt * 16 + l16] = (__bf16)p;
        }
      // no barrier: Ps rows [wid*16, wid*16+16) are wave-private.
      for (int r = 0; r < 4; ++r) {
        rsum[r] = redsum16(rsum[r]);          // DPP, VALU pipe
        l_i[r] = l_i[r] * alpha[r] + rsum[r];
        for (int nt = 0; nt < 4; ++nt) oacc[nt][r] *= alpha[r];
      }

      __builtin_amdgcn_s_setprio(1);
      for (int ks = 0; ks < 2; ++ks) {
        bf16x8 pf = *(const bf16x8*)
            &Ps[(wid * 16 + l16) * 72 + ks * 32 + quad * 8];
        for (int nt = 0; nt < 4; ++nt) {
          bf16x8 vf = *(const bf16x8*)
              &Vs[(nt * 16 + l16) * 72 + ks * 32 + quad * 8];
          oacc[nt] = __builtin_amdgcn_mfma_f32_16x16x32_bf16(
              pf, vf, oacc[nt], 0, 0, 0);
        }
      }
      __builtin_amdgcn_s_setprio(0);
    }

    // coalesced output: oacc -> Ps -> full-line b128 stores.
    for (int r = 0; r < 4; ++r) {
      float inv = 1.f / l_i[r];
      for (int nt = 0; nt < 4; ++nt)
        Ps[(wid * 16 + 4 * quad + r) * 72 + nt * 16 + l16] =
            (__bf16)(oacc[nt][r] * inv);
    }
    __syncthreads();
    {
      int row = tid >> 3, ch = tid & 7;        // 32 rows x 8 chunks
      size_t g0 = (rowb + q0 + row) * 1024 + h * 64 + ch * 8;
      *(bf16x8*)&QA[g0]                   = *(const bf16x8*)&Ps[row * 72 + ch * 8];
      *(bf16x8*)&QA[g0 + (size_t)32 * 1024] =
          *(const bf16x8*)&Ps[(row + 32) * 72 + ch * 8];
    }
    __syncthreads();   // isolate passes: Ps reads done before pass-2 writes
  }
}

// ---------------------------------------------------------------------------
// Output GEMM: out[m][n] = sum_k AO[m][k]*Wo[n][k], fp32 out, full-line f32x4.
// ---------------------------------------------------------------------------
__global__ __launch_bounds__(256) void gemm_out(
    const __bf16* __restrict__ AO, const __bf16* __restrict__ Wob,
    float* __restrict__ Of)
{
  __shared__ __bf16 As[128 * 32];
  __shared__ __bf16 Bs[128 * 32];
  __shared__ float  EsF[4 * 16 * 68];

  const int tid  = threadIdx.x;
  const int lane = tid & 63;
  const int wid  = tid >> 6;
  const int quad = lane >> 4;
  const int l16  = lane & 15;
  const int wm   = (wid >> 1) * 64;
  const int wn   = (wid & 1) * 64;
  const int lin = blockIdx.x;           // 256 blocks
  const int n0  = (lin & 7) * 128;
  const int m0  = (lin >> 3) * 128;

  const int r0 = tid >> 2, c0 = tid & 3;
  const int r1 = (tid + 256) >> 2;

  f32x4 acc[4][4];
  for (int i = 0; i < 4; ++i)
    for (int j = 0; j < 4; ++j) acc[i][j] = zero4();

  for (int k0 = 0; k0 < 1024; k0 += 32) {
    __syncthreads();
    GLDS16(AO  + (size_t)(m0 + r0) * 1024 + k0 + c0 * 8, &As[(size_t)tid * 8]);
    GLDS16(AO  + (size_t)(m0 + r1) * 1024 + k0 + c0 * 8, &As[(size_t)(tid + 256) * 8]);
    GLDS16(Wob + (size_t)(n0 + r0) * 1024 + k0 + c0 * 8, &Bs[(size_t)tid * 8]);
    GLDS16(Wob + (size_t)(n0 + r1) * 1024 + k0 + c0 * 8, &Bs[(size_t)(tid + 256) * 8]);
    __syncthreads();

    bf16x8 af[4], bfr[4];
    for (int i = 0; i < 4; ++i)
      af[i] = *(const bf16x8*)&As[(wm + i * 16 + l16) * 32 + quad * 8];
    for (int i = 0; i < 4; ++i)
      bfr[i] = *(const bf16x8*)&Bs[(wn + i * 16 + l16) * 32 + quad * 8];
    for (int mt = 0; mt < 4; ++mt)
      for (int nt = 0; nt < 4; ++nt)
        acc[mt][nt] = __builtin_amdgcn_mfma_f32_16x16x32_bf16(
            af[mt], bfr[nt], acc[mt][nt], 0, 0, 0);
  }

  float* es = &EsF[wid * 1088];         // 16 x 68 f32, per-wave private
  const int rl = lane >> 4, ch = lane & 15;
  for (int mt = 0; mt < 4; ++mt) {
    for (int nt = 0; nt < 4; ++nt)
      for (int r = 0; r < 4; ++r)
        es[(4 * quad + r) * 68 + nt * 16 + l16] = acc[mt][nt][r];
    size_t g0 = (size_t)(m0 + wm + mt * 16 + rl) * 1024 + n0 + wn + ch * 4;
    *(f32x4*)&Of[g0]             = *(const f32x4*)&es[rl * 68 + ch * 4];
    *(f32x4*)&Of[g0 + 4 * 1024]  = *(const f32x4*)&es[(rl + 4) * 68 + ch * 4];
    *(f32x4*)&Of[g0 + 8 * 1024]  = *(const f32x4*)&es[(rl + 8) * 68 + ch * 4];
    *(f32x4*)&Of[g0 + 12 * 1024] = *(const f32x4*)&es[(rl + 12) * 68 + ch * 4];
  }
}

// copy 8 bf16/lane
__global__ __launch_bounds__(256) void copy_bf16x8(
    const __bf16* __restrict__ src, __bf16* __restrict__ dst)
{
  size_t i = ((size_t)blockIdx.x * 256 + threadIdx.x) * 8;
  *(bf16x8*)&dst[i] = *(const bf16x8*)&src[i];
}

// ---------------------------------------------------------------------------
extern "C" void kernel_launch(void* const* d_in, const int* in_sizes, int n_in,
                              void* d_out, int out_size, void* d_ws, size_t ws_size,
                              hipStream_t stream) {
  const float* x  = (const float*)d_in[0];
  const float* Wq = (const float*)d_in[1];
  const float* Wk = (const float*)d_in[2];
  const float* Wv = (const float*)d_in[3];
  const float* Wo = (const float*)d_in[4];
  float* out = (float*)d_out;

  const size_t NELT = (size_t)4194304;             // 4M elems (8 MiB bf16)
  __bf16* Qp = (__bf16*)d_ws;        // plain Q, becomes AO in-place
  __bf16* Kp = Qp + NELT;            // plain K, later holds Wo bf16
  __bf16* Vt = Kp + NELT;            // V^T [bh][d][t]
  __bf16* xb = (__bf16*)d_out;       // d_out[0:8MB) scratch: x bf16
  __bf16* Wb = xb + NELT;            // d_out[8:16MB): W* bf16

  prep<<<dim3(4096), 256, 0, stream>>>(x, Wq, Wk, Wv, Wo, xb, Wb);
  gemm_qkv<<<dim3(768), 256, 0, stream>>>(xb, Wb, Qp, Kp, Vt);
  attn_fwd<<<dim3(512), 256, 0, stream>>>(Qp, Kp, Vt);
  copy_bf16x8<<<dim3(512), 256, 0, stream>>>(Wb + 3 * NELT / 4, Kp);
  gemm_out<<<dim3(256), 256, 0, stream>>>(Qp, Kp, out);
}

// Round 4
// 200.278 us; speedup vs baseline: 1.0598x; 1.0595x over previous
//
#include <hip/hip_runtime.h>
#include <stdint.h>

// MultiHeadAttention w/ RoPE, causal. B=2, T=2048, C=1024, H=16, Dh=64.
// Round 16: swapped-QK^T in-register softmax (T12 core) + defer-max (T13).
//  S^T = mfma(K,Q) — same registers, A/B fragment maps are identical — puts
//  q in lane idx: row-max/sum in-register (15 ops + 2 shfl_xor) instead of
//  DPP trees; m/l/alpha per-lane scalars; P written as 4x ds_write_b64
//  (contiguous r) instead of 16x ds_write_b16. Defer-max skips alpha/rescale
//  when __all(rmax <= m+8) (exp2 domain, P bounded by 2^8).
//  Keeps R15: XCD swizzle (FETCH 120->12MB verified), Q pre-scale, setprio.
//  Keeps R13/14: causal pairing, T14 prefetch, exp2 softmax, native trig.

typedef float  f32x4  __attribute__((ext_vector_type(4)));
typedef __bf16 bf16x8 __attribute__((ext_vector_type(8)));
typedef __bf16 bf16x4 __attribute__((ext_vector_type(4)));

#define GLDS16(gp, lp)                                                         \
  __builtin_amdgcn_global_load_lds(                                            \
      (const __attribute__((address_space(1))) void*)(gp),                     \
      (__attribute__((address_space(3))) void*)(lp), 16, 0, 0)

static __device__ __forceinline__ f32x4 zero4() {
  f32x4 z = {0.f, 0.f, 0.f, 0.f};
  return z;
}

static __device__ __forceinline__ bf16x8 cvt8(const float* __restrict__ p) {
  f32x4 u = *(const f32x4*)p;
  f32x4 v = *(const f32x4*)(p + 4);
  bf16x8 o;
#pragma unroll
  for (int j = 0; j < 4; ++j) o[j] = (__bf16)u[j];
#pragma unroll
  for (int j = 0; j < 4; ++j) o[4 + j] = (__bf16)v[j];
  return o;
}

// ---------------------------------------------------------------------------
// Prepass: x (4M f32) -> xb bf16; Wq/Wk/Wv/Wo (1M f32 each) -> Wb bf16[4][1M].
// ---------------------------------------------------------------------------
__global__ __launch_bounds__(256) void prep(
    const float* __restrict__ x,
    const float* __restrict__ Wq, const float* __restrict__ Wk,
    const float* __restrict__ Wv, const float* __restrict__ Wo,
    __bf16* __restrict__ xb, __bf16* __restrict__ Wb)
{
  size_t g = ((size_t)blockIdx.x * 256 + threadIdx.x) * 8;
  if (g < (size_t)4194304) {
    *(bf16x8*)&xb[g] = cvt8(x + g);
  } else {
    size_t j = g - 4194304;
    int w = (int)(j >> 20);
    size_t off = j & 1048575;
    const float* src = (w == 0) ? Wq : (w == 1) ? Wk : (w == 2) ? Wv : Wo;
    *(bf16x8*)&Wb[(size_t)w * 1048576 + off] = cvt8(src + off);
  }
}

// ---------------------------------------------------------------------------
// QKV GEMM (bf16 x bf16): C[m][n] = sum_k xb[m][k]*W[n][k]. 128x128, BK=32,
// GLDS16 staging. z<2: RoPE fused (Q pre-scaled by 0.125*log2e), plain store
// Qp/Kp. z=2: V^T [bh][d][t]. Full-line b128 stores via per-wave LDS tiles.
// ---------------------------------------------------------------------------
__global__ __launch_bounds__(256) void gemm_qkv(
    const __bf16* __restrict__ xb, const __bf16* __restrict__ Wb,
    __bf16* __restrict__ Qp, __bf16* __restrict__ Kp, __bf16* __restrict__ Vt)
{
  __shared__ __bf16 As[128 * 32];
  __shared__ __bf16 Bs[128 * 32];
  __shared__ __bf16 Es[4 * 16 * 72];   // per-wave 16x72 transpose tile

  const int tid  = threadIdx.x;
  const int lane = tid & 63;
  const int wid  = tid >> 6;
  const int quad = lane >> 4;
  const int l16  = lane & 15;
  const int wm   = (wid >> 1) * 64;
  const int wn   = (wid & 1) * 64;

  const int lin = blockIdx.x;           // 768 blocks
  const int n0  = (lin & 7) * 128;
  const int r2  = lin >> 3;
  const int z   = r2 % 3;
  const int m0  = (r2 / 3) * 128;
  const __bf16* Bt = Wb + (size_t)z * 1048576;

  const int r0 = tid >> 2, c0 = tid & 3;
  const int r1 = (tid + 256) >> 2;

  f32x4 acc[4][4];
  for (int i = 0; i < 4; ++i)
    for (int j = 0; j < 4; ++j) acc[i][j] = zero4();

  for (int k0 = 0; k0 < 1024; k0 += 32) {
    __syncthreads();
    GLDS16(xb + (size_t)(m0 + r0) * 1024 + k0 + c0 * 8, &As[(size_t)tid * 8]);
    GLDS16(xb + (size_t)(m0 + r1) * 1024 + k0 + c0 * 8, &As[(size_t)(tid + 256) * 8]);
    GLDS16(Bt + (size_t)(n0 + r0) * 1024 + k0 + c0 * 8, &Bs[(size_t)tid * 8]);
    GLDS16(Bt + (size_t)(n0 + r1) * 1024 + k0 + c0 * 8, &Bs[(size_t)(tid + 256) * 8]);
    __syncthreads();

    bf16x8 af[4], bfr[4];
    for (int i = 0; i < 4; ++i)
      af[i] = *(const bf16x8*)&As[(wm + i * 16 + l16) * 32 + quad * 8];
    for (int i = 0; i < 4; ++i)
      bfr[i] = *(const bf16x8*)&Bs[(wn + i * 16 + l16) * 32 + quad * 8];
    for (int mt = 0; mt < 4; ++mt)
      for (int nt = 0; nt < 4; ++nt)
        acc[mt][nt] = __builtin_amdgcn_mfma_f32_16x16x32_bf16(
            af[mt], bfr[nt], acc[mt][nt], 0, 0, 0);
  }

  // D layout: row = 4*quad + reg, col = l16 per 16x16 subtile.
  const int h = (n0 + wn) >> 6;
  __bf16* es = &Es[wid * 1152];        // 16 x 72, per-wave private
  const int rl = lane >> 3, ch = lane & 7;

  if (z < 2) {
    // fused RoPE; for Q (z==0) fold softmax scale 0.125*log2(e) into cv/sv.
    const float c0f = -13.287712379549449f / 32.0f;  // -log2(10000)/32
    const float f0 = exp2f((float)l16 * c0f);
    const float f1 = exp2f((float)(16 + l16) * c0f);
    const float SC = (z == 0) ? 0.125f * 1.44269504088896340736f : 1.0f;
    for (int mt = 0; mt < 4; ++mt)
      for (int r = 0; r < 4; ++r) {
        int gm = m0 + wm + mt * 16 + 4 * quad + r;
        float t = (float)(gm & 2047);
        for (int nt = 0; nt < 2; ++nt) {
          float ang = t * (nt ? f1 : f0);
          float cv = __cosf(ang) * SC, sv = __sinf(ang) * SC;
          float lo = acc[mt][nt][r], hi = acc[mt][nt + 2][r];
          acc[mt][nt][r]     = lo * cv - hi * sv;
          acc[mt][nt + 2][r] = hi * cv + lo * sv;
        }
      }
    __bf16* dst = (z == 0) ? Qp : Kp;
    for (int mt = 0; mt < 4; ++mt) {
      for (int nt = 0; nt < 4; ++nt)
        for (int r = 0; r < 4; ++r)
          es[(4 * quad + r) * 72 + nt * 16 + l16] = (__bf16)acc[mt][nt][r];
      size_t g0 = (size_t)(m0 + wm + mt * 16 + rl) * 1024 + n0 + wn + ch * 8;
      *(bf16x8*)&dst[g0]            = *(const bf16x8*)&es[rl * 72 + ch * 8];
      *(bf16x8*)&dst[g0 + 8 * 1024] = *(const bf16x8*)&es[(rl + 8) * 72 + ch * 8];
    }
  } else {
    // V^T: Vt[(b*16+h)*64 + d][t]
    const int b = m0 >> 11;
    const size_t hb = (size_t)(b * 16 + h) * 64;
    const int tt = (m0 + wm) & 2047;
    for (int nt = 0; nt < 4; ++nt) {
      for (int mt = 0; mt < 4; ++mt)
        for (int r = 0; r < 4; ++r)
          es[l16 * 72 + mt * 16 + 4 * quad + r] = (__bf16)acc[mt][nt][r];
      size_t g0 = (hb + nt * 16 + rl) * 2048 + tt + ch * 8;
      *(bf16x8*)&Vt[g0]                     = *(const bf16x8*)&es[rl * 72 + ch * 8];
      *(bf16x8*)&Vt[g0 + (size_t)8 * 2048]  = *(const bf16x8*)&es[(rl + 8) * 72 + ch * 8];
    }
  }
}

// ---------------------------------------------------------------------------
// Flash attention (causal). Q/K plain [b*t][1024] (head at col h*64),
// V^T [bh][d][t]. AO in-place into QA. Full-line output stores via Ps.
// Swapped QK^T: sacc = mfma(K,Q) => S^T, lane holds col q=l16, rows
// kpos=mt*16+4*quad+r. Softmax in-register; P stored via ds_write_b64.
// ---------------------------------------------------------------------------
__global__ __launch_bounds__(256) void attn_fwd(
    __bf16* QA, const __bf16* __restrict__ Kp,
    const __bf16* __restrict__ Vt)
{
  __shared__ __bf16 Ks[64 * 72];   // [kpos][d]
  __shared__ __bf16 Vs[64 * 72];   // [d][kpos]
  __shared__ __bf16 Ps[64 * 72];   // [q][kpos] / output transpose buffer

  const int tid  = threadIdx.x;
  const int lane = tid & 63, wid = tid >> 6;
  const int quad = lane >> 4, l16 = lane & 15;

  // XCD-aware decode: all blocks of one bh share linearID%8 -> one XCD.
  const int L  = blockIdx.x;                 // 0..511
  const int Lp = (L & 7) * 64 + (L >> 3);
  const int bh = Lp >> 4;                    // 4 heads per XCD
  const int xq = Lp & 15;                    // pair index 0..15
  const int b = bh >> 4, h = bh & 15;

  const size_t rowb = (size_t)b * 2048;
  const __bf16* Vb = Vt + (size_t)bh * 64 * 2048;

  const int sr0 = tid >> 3, sc0 = tid & 7;
  const int sr1 = (tid + 256) >> 3;

  for (int pass = 0; pass < 2; ++pass) {
    const int qb = pass ? (31 - xq) : xq;
    const int q0 = qb * 64;

    bf16x8 qa[2];
    for (int ks = 0; ks < 2; ++ks)
      qa[ks] = *(const bf16x8*)
          &QA[(rowb + q0 + wid * 16 + l16) * 1024 + h * 64 + ks * 32 + quad * 8];

    f32x4 oacc[4];
    for (int i = 0; i < 4; ++i) oacc[i] = zero4();
    float m_i = -1e30f, l_i = 0.f;        // per-lane, q = wid*16 + l16

    const int kcmax = qb;

    // prologue: prefetch KV tile 0
    bf16x8 k0v = *(const bf16x8*)&Kp[(rowb + sr0) * 1024 + h * 64 + sc0 * 8];
    bf16x8 k1v = *(const bf16x8*)&Kp[(rowb + sr1) * 1024 + h * 64 + sc0 * 8];
    bf16x8 v0v = *(const bf16x8*)&Vb[(size_t)sr0 * 2048 + sc0 * 8];
    bf16x8 v1v = *(const bf16x8*)&Vb[(size_t)sr1 * 2048 + sc0 * 8];

    for (int kc = 0; kc <= kcmax; ++kc) {
      __syncthreads();   // previous tile's LDS reads complete (all waves)
      *(bf16x8*)&Ks[sr0 * 72 + sc0 * 8] = k0v;
      *(bf16x8*)&Ks[sr1 * 72 + sc0 * 8] = k1v;
      *(bf16x8*)&Vs[sr0 * 72 + sc0 * 8] = v0v;
      *(bf16x8*)&Vs[sr1 * 72 + sc0 * 8] = v1v;
      __syncthreads();

      // T14: issue next tile's loads now; latency hides under compute below.
      if (kc < kcmax) {
        const int kn = kc + 1;
        k0v = *(const bf16x8*)&Kp[(rowb + kn * 64 + sr0) * 1024 + h * 64 + sc0 * 8];
        k1v = *(const bf16x8*)&Kp[(rowb + kn * 64 + sr1) * 1024 + h * 64 + sc0 * 8];
        v0v = *(const bf16x8*)&Vb[(size_t)sr0 * 2048 + kn * 64 + sc0 * 8];
        v1v = *(const bf16x8*)&Vb[(size_t)sr1 * 2048 + kn * 64 + sc0 * 8];
      }

      // S^T = K * Q^T : lane holds col q=l16, rows kpos = mt*16+4*quad+r.
      f32x4 sacc[4];
      for (int i = 0; i < 4; ++i) sacc[i] = zero4();
      __builtin_amdgcn_s_setprio(1);
      for (int ks = 0; ks < 2; ++ks) {
        bf16x8 qf = qa[ks];
        for (int mt = 0; mt < 4; ++mt) {
          bf16x8 kf = *(const bf16x8*)
              &Ks[(mt * 16 + l16) * 72 + ks * 32 + quad * 8];
          sacc[mt] = __builtin_amdgcn_mfma_f32_16x16x32_bf16(
              kf, qf, sacc[mt], 0, 0, 0);
        }
      }
      __builtin_amdgcn_s_setprio(0);

      const bool diag = (kc == kcmax);
      float rmax = -1e30f;
      const int iq = wid * 16 + l16;        // q row within 64-tile
      for (int mt = 0; mt < 4; ++mt)
        for (int r = 0; r < 4; ++r) {
          float s = sacc[mt][r];            // pre-scaled via Q
          if (diag && (mt * 16 + 4 * quad + r > iq)) s = -1e30f;
          sacc[mt][r] = s;
          rmax = fmaxf(rmax, s);
        }
      // cross-quad combine (lanes l16 +/- 16,32 hold other kpos rows)
      rmax = fmaxf(rmax, __shfl_xor(rmax, 16, 64));
      rmax = fmaxf(rmax, __shfl_xor(rmax, 32, 64));

      // T13 defer-max: skip rescale while max growth bounded (P <= 2^8).
      const bool noresc = __all(rmax <= m_i + 8.0f);
      float alpha = 1.0f;
      if (!noresc) {
        float nm = fmaxf(m_i, rmax);
        alpha = __builtin_amdgcn_exp2f(m_i - nm);
        m_i = nm;
      }

      float rsum = 0.f;
      for (int mt = 0; mt < 4; ++mt) {
        bf16x4 pw;
        for (int r = 0; r < 4; ++r) {
          float p = __builtin_amdgcn_exp2f(sacc[mt][r] - m_i);
          rsum += p;
          pw[r] = (__bf16)p;
        }
        // lane's 4 r-values are contiguous kpos: one b64 write
        *(bf16x4*)&Ps[iq * 72 + mt * 16 + 4 * quad] = pw;
      }
      rsum += __shfl_xor(rsum, 16, 64);
      rsum += __shfl_xor(rsum, 32, 64);

      if (!noresc) {
        l_i = l_i * alpha + rsum;
        for (int r = 0; r < 4; ++r) {
          float a_r = __shfl(alpha, 4 * quad + r, 64);  // alpha for row q=4q+r
          for (int nt = 0; nt < 4; ++nt) oacc[nt][r] *= a_r;
        }
      } else {
        l_i += rsum;
      }

      // PV: O[q][d], pf = P[q][kpos] (wave-private rows of Ps, same-wave
      // write->read ordered by lgkmcnt).
      __builtin_amdgcn_s_setprio(1);
      for (int ks = 0; ks < 2; ++ks) {
        bf16x8 pf = *(const bf16x8*)
            &Ps[(wid * 16 + l16) * 72 + ks * 32 + quad * 8];
        for (int nt = 0; nt < 4; ++nt) {
          bf16x8 vf = *(const bf16x8*)
              &Vs[(nt * 16 + l16) * 72 + ks * 32 + quad * 8];
          oacc[nt] = __builtin_amdgcn_mfma_f32_16x16x32_bf16(
              pf, vf, oacc[nt], 0, 0, 0);
        }
      }
      __builtin_amdgcn_s_setprio(0);
    }

    // coalesced output: oacc -> Ps -> full-line b128 stores.
    {
      float invl = 1.0f / l_i;              // per-lane, q = wid*16+l16
      for (int r = 0; r < 4; ++r) {
        float inv_r = __shfl(invl, 4 * quad + r, 64);
        for (int nt = 0; nt < 4; ++nt)
          Ps[(wid * 16 + 4 * quad + r) * 72 + nt * 16 + l16] =
              (__bf16)(oacc[nt][r] * inv_r);
      }
    }
    __syncthreads();
    {
      int row = tid >> 3, ch = tid & 7;        // 32 rows x 8 chunks
      size_t g0 = (rowb + q0 + row) * 1024 + h * 64 + ch * 8;
      *(bf16x8*)&QA[g0]                   = *(const bf16x8*)&Ps[row * 72 + ch * 8];
      *(bf16x8*)&QA[g0 + (size_t)32 * 1024] =
          *(const bf16x8*)&Ps[(row + 32) * 72 + ch * 8];
    }
    __syncthreads();   // isolate passes: Ps reads done before pass-2 writes
  }
}

// ---------------------------------------------------------------------------
// Output GEMM: out[m][n] = sum_k AO[m][k]*Wo[n][k], fp32 out, full-line f32x4.
// ---------------------------------------------------------------------------
__global__ __launch_bounds__(256) void gemm_out(
    const __bf16* __restrict__ AO, const __bf16* __restrict__ Wob,
    float* __restrict__ Of)
{
  __shared__ __bf16 As[128 * 32];
  __shared__ __bf16 Bs[128 * 32];
  __shared__ float  EsF[4 * 16 * 68];

  const int tid  = threadIdx.x;
  const int lane = tid & 63;
  const int wid  = tid >> 6;
  const int quad = lane >> 4;
  const int l16  = lane & 15;
  const int wm   = (wid >> 1) * 64;
  const int wn   = (wid & 1) * 64;
  const int lin = blockIdx.x;           // 256 blocks
  const int n0  = (lin & 7) * 128;
  const int m0  = (lin >> 3) * 128;

  const int r0 = tid >> 2, c0 = tid & 3;
  const int r1 = (tid + 256) >> 2;

  f32x4 acc[4][4];
  for (int i = 0; i < 4; ++i)
    for (int j = 0; j < 4; ++j) acc[i][j] = zero4();

  for (int k0 = 0; k0 < 1024; k0 += 32) {
    __syncthreads();
    GLDS16(AO  + (size_t)(m0 + r0) * 1024 + k0 + c0 * 8, &As[(size_t)tid * 8]);
    GLDS16(AO  + (size_t)(m0 + r1) * 1024 + k0 + c0 * 8, &As[(size_t)(tid + 256) * 8]);
    GLDS16(Wob + (size_t)(n0 + r0) * 1024 + k0 + c0 * 8, &Bs[(size_t)tid * 8]);
    GLDS16(Wob + (size_t)(n0 + r1) * 1024 + k0 + c0 * 8, &Bs[(size_t)(tid + 256) * 8]);
    __syncthreads();

    bf16x8 af[4], bfr[4];
    for (int i = 0; i < 4; ++i)
      af[i] = *(const bf16x8*)&As[(wm + i * 16 + l16) * 32 + quad * 8];
    for (int i = 0; i < 4; ++i)
      bfr[i] = *(const bf16x8*)&Bs[(wn + i * 16 + l16) * 32 + quad * 8];
    for (int mt = 0; mt < 4; ++mt)
      for (int nt = 0; nt < 4; ++nt)
        acc[mt][nt] = __builtin_amdgcn_mfma_f32_16x16x32_bf16(
            af[mt], bfr[nt], acc[mt][nt], 0, 0, 0);
  }

  float* es = &EsF[wid * 1088];         // 16 x 68 f32, per-wave private
  const int rl = lane >> 4, ch = lane & 15;
  for (int mt = 0; mt < 4; ++mt) {
    for (int nt = 0; nt < 4; ++nt)
      for (int r = 0; r < 4; ++r)
        es[(4 * quad + r) * 68 + nt * 16 + l16] = acc[mt][nt][r];
    size_t g0 = (size_t)(m0 + wm + mt * 16 + rl) * 1024 + n0 + wn + ch * 4;
    *(f32x4*)&Of[g0]             = *(const f32x4*)&es[rl * 68 + ch * 4];
    *(f32x4*)&Of[g0 + 4 * 1024]  = *(const f32x4*)&es[(rl + 4) * 68 + ch * 4];
    *(f32x4*)&Of[g0 + 8 * 1024]  = *(const f32x4*)&es[(rl + 8) * 68 + ch * 4];
    *(f32x4*)&Of[g0 + 12 * 1024] = *(const f32x4*)&es[(rl + 12) * 68 + ch * 4];
  }
}

// copy 8 bf16/lane
__global__ __launch_bounds__(256) void copy_bf16x8(
    const __bf16* __restrict__ src, __bf16* __restrict__ dst)
{
  size_t i = ((size_t)blockIdx.x * 256 + threadIdx.x) * 8;
  *(bf16x8*)&dst[i] = *(const bf16x8*)&src[i];
}

// ---------------------------------------------------------------------------
extern "C" void kernel_launch(void* const* d_in, const int* in_sizes, int n_in,
                              void* d_out, int out_size, void* d_ws, size_t ws_size,
                              hipStream_t stream) {
  const float* x  = (const float*)d_in[0];
  const float* Wq = (const float*)d_in[1];
  const float* Wk = (const float*)d_in[2];
  const float* Wv = (const float*)d_in[3];
  const float* Wo = (const float*)d_in[4];
  float* out = (float*)d_out;

  const size_t NELT = (size_t)4194304;             // 4M elems (8 MiB bf16)
  __bf16* Qp = (__bf16*)d_ws;        // plain Q, becomes AO in-place
  __bf16* Kp = Qp + NELT;            // plain K, later holds Wo bf16
  __bf16* Vt = Kp + NELT;            // V^T [bh][d][t]
  __bf16* xb = (__bf16*)d_out;       // d_out[0:8MB) scratch: x bf16
  __bf16* Wb = xb + NELT;            // d_out[8:16MB): W* bf16

  prep<<<dim3(4096), 256, 0, stream>>>(x, Wq, Wk, Wv, Wo, xb, Wb);
  gemm_qkv<<<dim3(768), 256, 0, stream>>>(xb, Wb, Qp, Kp, Vt);
  attn_fwd<<<dim3(512), 256, 0, stream>>>(Qp, Kp, Vt);
  copy_bf16x8<<<dim3(512), 256, 0, stream>>>(Wb + 3 * NELT / 4, Kp);
  gemm_out<<<dim3(256), 256, 0, stream>>>(Qp, Kp, out);
}

// Round 5
// 198.422 us; speedup vs baseline: 1.0697x; 1.0094x over previous
//
#include <hip/hip_runtime.h>
#include <stdint.h>

// MultiHeadAttention w/ RoPE, causal. B=2, T=2048, C=1024, H=16, Dh=64.
// Round 17: attn dual-tile fusion + K/V double-buffer.
//  Each block processes its causal pair (xq, 31-xq) CONCURRENTLY: one K/V
//  staging serves both q-tiles (staged iters 33 -> 32-xq, avg 24.5), and the
//  two tiles' QK/softmax/PV chains are independent -> MFMA of one hides the
//  VALU softmax of the other (ILP instead of occupancy). K/V double-buffered:
//  write tile kc+1 into buf^1 while computing buf -> ONE barrier per iter
//  (66 -> ~25 barriers/block).
//  Keeps R16: swapped-QK^T in-register softmax, defer-max, b64 P-writes.
//  Keeps R15: XCD swizzle, Q pre-scale by 0.125*log2e, setprio.
//  Keeps R13/14: T14 reg prefetch, exp2 softmax, native trig epilogues.

typedef float  f32x4  __attribute__((ext_vector_type(4)));
typedef __bf16 bf16x8 __attribute__((ext_vector_type(8)));
typedef __bf16 bf16x4 __attribute__((ext_vector_type(4)));

#define GLDS16(gp, lp)                                                         \
  __builtin_amdgcn_global_load_lds(                                            \
      (const __attribute__((address_space(1))) void*)(gp),                     \
      (__attribute__((address_space(3))) void*)(lp), 16, 0, 0)

static __device__ __forceinline__ f32x4 zero4() {
  f32x4 z = {0.f, 0.f, 0.f, 0.f};
  return z;
}

static __device__ __forceinline__ bf16x8 cvt8(const float* __restrict__ p) {
  f32x4 u = *(const f32x4*)p;
  f32x4 v = *(const f32x4*)(p + 4);
  bf16x8 o;
#pragma unroll
  for (int j = 0; j < 4; ++j) o[j] = (__bf16)u[j];
#pragma unroll
  for (int j = 0; j < 4; ++j) o[4 + j] = (__bf16)v[j];
  return o;
}

// ---------------------------------------------------------------------------
// Prepass: x (4M f32) -> xb bf16; Wq/Wk/Wv/Wo (1M f32 each) -> Wb bf16[4][1M].
// ---------------------------------------------------------------------------
__global__ __launch_bounds__(256) void prep(
    const float* __restrict__ x,
    const float* __restrict__ Wq, const float* __restrict__ Wk,
    const float* __restrict__ Wv, const float* __restrict__ Wo,
    __bf16* __restrict__ xb, __bf16* __restrict__ Wb)
{
  size_t g = ((size_t)blockIdx.x * 256 + threadIdx.x) * 8;
  if (g < (size_t)4194304) {
    *(bf16x8*)&xb[g] = cvt8(x + g);
  } else {
    size_t j = g - 4194304;
    int w = (int)(j >> 20);
    size_t off = j & 1048575;
    const float* src = (w == 0) ? Wq : (w == 1) ? Wk : (w == 2) ? Wv : Wo;
    *(bf16x8*)&Wb[(size_t)w * 1048576 + off] = cvt8(src + off);
  }
}

// ---------------------------------------------------------------------------
// QKV GEMM (bf16 x bf16): C[m][n] = sum_k xb[m][k]*W[n][k]. 128x128, BK=32,
// GLDS16 staging. z<2: RoPE fused (Q pre-scaled by 0.125*log2e), plain store
// Qp/Kp. z=2: V^T [bh][d][t]. Full-line b128 stores via per-wave LDS tiles.
// ---------------------------------------------------------------------------
__global__ __launch_bounds__(256) void gemm_qkv(
    const __bf16* __restrict__ xb, const __bf16* __restrict__ Wb,
    __bf16* __restrict__ Qp, __bf16* __restrict__ Kp, __bf16* __restrict__ Vt)
{
  __shared__ __bf16 As[128 * 32];
  __shared__ __bf16 Bs[128 * 32];
  __shared__ __bf16 Es[4 * 16 * 72];   // per-wave 16x72 transpose tile

  const int tid  = threadIdx.x;
  const int lane = tid & 63;
  const int wid  = tid >> 6;
  const int quad = lane >> 4;
  const int l16  = lane & 15;
  const int wm   = (wid >> 1) * 64;
  const int wn   = (wid & 1) * 64;

  const int lin = blockIdx.x;           // 768 blocks
  const int n0  = (lin & 7) * 128;
  const int r2  = lin >> 3;
  const int z   = r2 % 3;
  const int m0  = (r2 / 3) * 128;
  const __bf16* Bt = Wb + (size_t)z * 1048576;

  const int r0 = tid >> 2, c0 = tid & 3;
  const int r1 = (tid + 256) >> 2;

  f32x4 acc[4][4];
  for (int i = 0; i < 4; ++i)
    for (int j = 0; j < 4; ++j) acc[i][j] = zero4();

  for (int k0 = 0; k0 < 1024; k0 += 32) {
    __syncthreads();
    GLDS16(xb + (size_t)(m0 + r0) * 1024 + k0 + c0 * 8, &As[(size_t)tid * 8]);
    GLDS16(xb + (size_t)(m0 + r1) * 1024 + k0 + c0 * 8, &As[(size_t)(tid + 256) * 8]);
    GLDS16(Bt + (size_t)(n0 + r0) * 1024 + k0 + c0 * 8, &Bs[(size_t)tid * 8]);
    GLDS16(Bt + (size_t)(n0 + r1) * 1024 + k0 + c0 * 8, &Bs[(size_t)(tid + 256) * 8]);
    __syncthreads();

    bf16x8 af[4], bfr[4];
    for (int i = 0; i < 4; ++i)
      af[i] = *(const bf16x8*)&As[(wm + i * 16 + l16) * 32 + quad * 8];
    for (int i = 0; i < 4; ++i)
      bfr[i] = *(const bf16x8*)&Bs[(wn + i * 16 + l16) * 32 + quad * 8];
    for (int mt = 0; mt < 4; ++mt)
      for (int nt = 0; nt < 4; ++nt)
        acc[mt][nt] = __builtin_amdgcn_mfma_f32_16x16x32_bf16(
            af[mt], bfr[nt], acc[mt][nt], 0, 0, 0);
  }

  // D layout: row = 4*quad + reg, col = l16 per 16x16 subtile.
  const int h = (n0 + wn) >> 6;
  __bf16* es = &Es[wid * 1152];        // 16 x 72, per-wave private
  const int rl = lane >> 3, ch = lane & 7;

  if (z < 2) {
    // fused RoPE; for Q (z==0) fold softmax scale 0.125*log2(e) into cv/sv.
    const float c0f = -13.287712379549449f / 32.0f;  // -log2(10000)/32
    const float f0 = exp2f((float)l16 * c0f);
    const float f1 = exp2f((float)(16 + l16) * c0f);
    const float SC = (z == 0) ? 0.125f * 1.44269504088896340736f : 1.0f;
    for (int mt = 0; mt < 4; ++mt)
      for (int r = 0; r < 4; ++r) {
        int gm = m0 + wm + mt * 16 + 4 * quad + r;
        float t = (float)(gm & 2047);
        for (int nt = 0; nt < 2; ++nt) {
          float ang = t * (nt ? f1 : f0);
          float cv = __cosf(ang) * SC, sv = __sinf(ang) * SC;
          float lo = acc[mt][nt][r], hi = acc[mt][nt + 2][r];
          acc[mt][nt][r]     = lo * cv - hi * sv;
          acc[mt][nt + 2][r] = hi * cv + lo * sv;
        }
      }
    __bf16* dst = (z == 0) ? Qp : Kp;
    for (int mt = 0; mt < 4; ++mt) {
      for (int nt = 0; nt < 4; ++nt)
        for (int r = 0; r < 4; ++r)
          es[(4 * quad + r) * 72 + nt * 16 + l16] = (__bf16)acc[mt][nt][r];
      size_t g0 = (size_t)(m0 + wm + mt * 16 + rl) * 1024 + n0 + wn + ch * 8;
      *(bf16x8*)&dst[g0]            = *(const bf16x8*)&es[rl * 72 + ch * 8];
      *(bf16x8*)&dst[g0 + 8 * 1024] = *(const bf16x8*)&es[(rl + 8) * 72 + ch * 8];
    }
  } else {
    // V^T: Vt[(b*16+h)*64 + d][t]
    const int b = m0 >> 11;
    const size_t hb = (size_t)(b * 16 + h) * 64;
    const int tt = (m0 + wm) & 2047;
    for (int nt = 0; nt < 4; ++nt) {
      for (int mt = 0; mt < 4; ++mt)
        for (int r = 0; r < 4; ++r)
          es[l16 * 72 + mt * 16 + 4 * quad + r] = (__bf16)acc[mt][nt][r];
      size_t g0 = (hb + nt * 16 + rl) * 2048 + tt + ch * 8;
      *(bf16x8*)&Vt[g0]                     = *(const bf16x8*)&es[rl * 72 + ch * 8];
      *(bf16x8*)&Vt[g0 + (size_t)8 * 2048]  = *(const bf16x8*)&es[(rl + 8) * 72 + ch * 8];
    }
  }
}

// ---------------------------------------------------------------------------
// Flash attention (causal). Q/K plain [b*t][1024] (head at col h*64),
// V^T [bh][d][t]. AO in-place into QA.
// Dual-tile: block handles q-tiles qlo=xq and qhi=31-xq concurrently; one
// staged K/V tile serves both (lo active while kc<=qlo). K/V double-buffered:
// ONE barrier per iter. Swapped-QK^T in-register softmax per tile.
// ---------------------------------------------------------------------------
__global__ __launch_bounds__(256) void attn_fwd(
    __bf16* QA, const __bf16* __restrict__ Kp,
    const __bf16* __restrict__ Vt)
{
  __shared__ __bf16 Ks[2][64 * 72];   // [buf][kpos][d]
  __shared__ __bf16 Vs[2][64 * 72];   // [buf][d][kpos]
  __shared__ __bf16 PsA[64 * 72];     // P / output transpose, tile lo
  __shared__ __bf16 PsB[64 * 72];     // P / output transpose, tile hi

  const int tid  = threadIdx.x;
  const int lane = tid & 63, wid = tid >> 6;
  const int quad = lane >> 4, l16 = lane & 15;

  // XCD-aware decode: all blocks of one bh share linearID%8 -> one XCD.
  const int L  = blockIdx.x;                 // 0..511
  const int Lp = (L & 7) * 64 + (L >> 3);
  const int bh = Lp >> 4;                    // 4 heads per XCD
  const int xq = Lp & 15;                    // pair index 0..15
  const int b = bh >> 4, h = bh & 15;

  const size_t rowb = (size_t)b * 2048;
  const __bf16* Vb = Vt + (size_t)bh * 64 * 2048;

  const int sr0 = tid >> 3, sc0 = tid & 7;
  const int sr1 = (tid + 256) >> 3;

  const int qlo = xq, qhi = 31 - xq;         // qhi >= 16 > qlo always
  const int q0lo = qlo * 64, q0hi = qhi * 64;
  const int iq = wid * 16 + l16;             // q row within a 64-tile

  bf16x8 qaL[2], qaH[2];
  for (int ks = 0; ks < 2; ++ks) {
    qaL[ks] = *(const bf16x8*)
        &QA[(rowb + q0lo + iq) * 1024 + h * 64 + ks * 32 + quad * 8];
    qaH[ks] = *(const bf16x8*)
        &QA[(rowb + q0hi + iq) * 1024 + h * 64 + ks * 32 + quad * 8];
  }

  f32x4 oaccL[4], oaccH[4];
  for (int i = 0; i < 4; ++i) { oaccL[i] = zero4(); oaccH[i] = zero4(); }
  float mL = -1e30f, lL = 0.f, mH = -1e30f, lH = 0.f;

  // prologue: tile 0 -> buf0 (direct), prefetch tile 1 -> regs.
  bf16x8 k0v, k1v, v0v, v1v;
  k0v = *(const bf16x8*)&Kp[(rowb + sr0) * 1024 + h * 64 + sc0 * 8];
  k1v = *(const bf16x8*)&Kp[(rowb + sr1) * 1024 + h * 64 + sc0 * 8];
  v0v = *(const bf16x8*)&Vb[(size_t)sr0 * 2048 + sc0 * 8];
  v1v = *(const bf16x8*)&Vb[(size_t)sr1 * 2048 + sc0 * 8];
  *(bf16x8*)&Ks[0][sr0 * 72 + sc0 * 8] = k0v;
  *(bf16x8*)&Ks[0][sr1 * 72 + sc0 * 8] = k1v;
  *(bf16x8*)&Vs[0][sr0 * 72 + sc0 * 8] = v0v;
  *(bf16x8*)&Vs[0][sr1 * 72 + sc0 * 8] = v1v;
  k0v = *(const bf16x8*)&Kp[(rowb + 64 + sr0) * 1024 + h * 64 + sc0 * 8];
  k1v = *(const bf16x8*)&Kp[(rowb + 64 + sr1) * 1024 + h * 64 + sc0 * 8];
  v0v = *(const bf16x8*)&Vb[(size_t)sr0 * 2048 + 64 + sc0 * 8];
  v1v = *(const bf16x8*)&Vb[(size_t)sr1 * 2048 + 64 + sc0 * 8];
  __syncthreads();

  for (int kc = 0; kc <= qhi; ++kc) {
    const int c = kc & 1;
    // stage tile kc+1 into buf c^1 (regs prefetched last iter / prologue)
    if (kc < qhi) {
      *(bf16x8*)&Ks[c ^ 1][sr0 * 72 + sc0 * 8] = k0v;
      *(bf16x8*)&Ks[c ^ 1][sr1 * 72 + sc0 * 8] = k1v;
      *(bf16x8*)&Vs[c ^ 1][sr0 * 72 + sc0 * 8] = v0v;
      *(bf16x8*)&Vs[c ^ 1][sr1 * 72 + sc0 * 8] = v1v;
    }
    // prefetch tile kc+2 -> regs (latency hides under compute below)
    if (kc + 2 <= qhi) {
      const int kn = kc + 2;
      k0v = *(const bf16x8*)&Kp[(rowb + kn * 64 + sr0) * 1024 + h * 64 + sc0 * 8];
      k1v = *(const bf16x8*)&Kp[(rowb + kn * 64 + sr1) * 1024 + h * 64 + sc0 * 8];
      v0v = *(const bf16x8*)&Vb[(size_t)sr0 * 2048 + kn * 64 + sc0 * 8];
      v1v = *(const bf16x8*)&Vb[(size_t)sr1 * 2048 + kn * 64 + sc0 * 8];
    }

    const bool doLo = (kc <= qlo);

    // ---- QK^T (swapped) tile HI, then tile LO: back-to-back MFMA ----
    f32x4 saccH[4], saccL[4];
    for (int i = 0; i < 4; ++i) saccH[i] = zero4();
    __builtin_amdgcn_s_setprio(1);
    for (int ks = 0; ks < 2; ++ks) {
      bf16x8 qf = qaH[ks];
      for (int mt = 0; mt < 4; ++mt) {
        bf16x8 kf = *(const bf16x8*)
            &Ks[c][(mt * 16 + l16) * 72 + ks * 32 + quad * 8];
        saccH[mt] = __builtin_amdgcn_mfma_f32_16x16x32_bf16(
            kf, qf, saccH[mt], 0, 0, 0);
      }
    }
    if (doLo) {
      for (int i = 0; i < 4; ++i) saccL[i] = zero4();
      for (int ks = 0; ks < 2; ++ks) {
        bf16x8 qf = qaL[ks];
        for (int mt = 0; mt < 4; ++mt) {
          bf16x8 kf = *(const bf16x8*)
              &Ks[c][(mt * 16 + l16) * 72 + ks * 32 + quad * 8];
          saccL[mt] = __builtin_amdgcn_mfma_f32_16x16x32_bf16(
              kf, qf, saccL[mt], 0, 0, 0);
        }
      }
    }
    __builtin_amdgcn_s_setprio(0);

    // ---- softmax tile HI (VALU; overlaps tile-LO MFMA drain) ----
    {
      const bool diag = (kc == qhi);
      float rmax = -1e30f;
      for (int mt = 0; mt < 4; ++mt)
        for (int r = 0; r < 4; ++r) {
          float s = saccH[mt][r];
          if (diag && (mt * 16 + 4 * quad + r > iq)) s = -1e30f;
          saccH[mt][r] = s;
          rmax = fmaxf(rmax, s);
        }
      rmax = fmaxf(rmax, __shfl_xor(rmax, 16, 64));
      rmax = fmaxf(rmax, __shfl_xor(rmax, 32, 64));
      const bool noresc = __all(rmax <= mH + 8.0f);
      float alpha = 1.0f;
      if (!noresc) {
        float nm = fmaxf(mH, rmax);
        alpha = __builtin_amdgcn_exp2f(mH - nm);
        mH = nm;
      }
      float rsum = 0.f;
      for (int mt = 0; mt < 4; ++mt) {
        bf16x4 pw;
        for (int r = 0; r < 4; ++r) {
          float p = __builtin_amdgcn_exp2f(saccH[mt][r] - mH);
          rsum += p;
          pw[r] = (__bf16)p;
        }
        *(bf16x4*)&PsB[iq * 72 + mt * 16 + 4 * quad] = pw;
      }
      rsum += __shfl_xor(rsum, 16, 64);
      rsum += __shfl_xor(rsum, 32, 64);
      if (!noresc) {
        lH = lH * alpha + rsum;
        for (int r = 0; r < 4; ++r) {
          float a_r = __shfl(alpha, 4 * quad + r, 64);
          for (int nt = 0; nt < 4; ++nt) oaccH[nt][r] *= a_r;
        }
      } else {
        lH += rsum;
      }
    }
    // ---- softmax tile LO ----
    if (doLo) {
      const bool diag = (kc == qlo);
      float rmax = -1e30f;
      for (int mt = 0; mt < 4; ++mt)
        for (int r = 0; r < 4; ++r) {
          float s = saccL[mt][r];
          if (diag && (mt * 16 + 4 * quad + r > iq)) s = -1e30f;
          saccL[mt][r] = s;
          rmax = fmaxf(rmax, s);
        }
      rmax = fmaxf(rmax, __shfl_xor(rmax, 16, 64));
      rmax = fmaxf(rmax, __shfl_xor(rmax, 32, 64));
      const bool noresc = __all(rmax <= mL + 8.0f);
      float alpha = 1.0f;
      if (!noresc) {
        float nm = fmaxf(mL, rmax);
        alpha = __builtin_amdgcn_exp2f(mL - nm);
        mL = nm;
      }
      float rsum = 0.f;
      for (int mt = 0; mt < 4; ++mt) {
        bf16x4 pw;
        for (int r = 0; r < 4; ++r) {
          float p = __builtin_amdgcn_exp2f(saccL[mt][r] - mL);
          rsum += p;
          pw[r] = (__bf16)p;
        }
        *(bf16x4*)&PsA[iq * 72 + mt * 16 + 4 * quad] = pw;
      }
      rsum += __shfl_xor(rsum, 16, 64);
      rsum += __shfl_xor(rsum, 32, 64);
      if (!noresc) {
        lL = lL * alpha + rsum;
        for (int r = 0; r < 4; ++r) {
          float a_r = __shfl(alpha, 4 * quad + r, 64);
          for (int nt = 0; nt < 4; ++nt) oaccL[nt][r] *= a_r;
        }
      } else {
        lL += rsum;
      }
    }

    // ---- PV tile HI, then tile LO (MFMA; LO softmax VALU drains under HI) --
    __builtin_amdgcn_s_setprio(1);
    for (int ks = 0; ks < 2; ++ks) {
      bf16x8 pf = *(const bf16x8*)
          &PsB[(wid * 16 + l16) * 72 + ks * 32 + quad * 8];
      for (int nt = 0; nt < 4; ++nt) {
        bf16x8 vf = *(const bf16x8*)
            &Vs[c][(nt * 16 + l16) * 72 + ks * 32 + quad * 8];
        oaccH[nt] = __builtin_amdgcn_mfma_f32_16x16x32_bf16(
            pf, vf, oaccH[nt], 0, 0, 0);
      }
    }
    if (doLo) {
      for (int ks = 0; ks < 2; ++ks) {
        bf16x8 pf = *(const bf16x8*)
            &PsA[(wid * 16 + l16) * 72 + ks * 32 + quad * 8];
        for (int nt = 0; nt < 4; ++nt) {
          bf16x8 vf = *(const bf16x8*)
              &Vs[c][(nt * 16 + l16) * 72 + ks * 32 + quad * 8];
          oaccL[nt] = __builtin_amdgcn_mfma_f32_16x16x32_bf16(
              pf, vf, oaccL[nt], 0, 0, 0);
        }
      }
    }
    __builtin_amdgcn_s_setprio(0);

    __syncthreads();   // buf c^1 writes done; buf c reads done
  }

  // epilogue: normalize into PsA/PsB (wave-private rows), one barrier,
  // then full-line b128 stores for both tiles.
  {
    float invL = 1.0f / lL, invH = 1.0f / lH;
    for (int r = 0; r < 4; ++r) {
      float iLr = __shfl(invL, 4 * quad + r, 64);
      float iHr = __shfl(invH, 4 * quad + r, 64);
      for (int nt = 0; nt < 4; ++nt) {
        PsA[(wid * 16 + 4 * quad + r) * 72 + nt * 16 + l16] =
            (__bf16)(oaccL[nt][r] * iLr);
        PsB[(wid * 16 + 4 * quad + r) * 72 + nt * 16 + l16] =
            (__bf16)(oaccH[nt][r] * iHr);
      }
    }
  }
  __syncthreads();
  {
    int row = tid >> 3, ch = tid & 7;        // 32 rows x 8 chunks
    size_t gLo = (rowb + q0lo + row) * 1024 + h * 64 + ch * 8;
    size_t gHi = (rowb + q0hi + row) * 1024 + h * 64 + ch * 8;
    *(bf16x8*)&QA[gLo] = *(const bf16x8*)&PsA[row * 72 + ch * 8];
    *(bf16x8*)&QA[gLo + (size_t)32 * 1024] =
        *(const bf16x8*)&PsA[(row + 32) * 72 + ch * 8];
    *(bf16x8*)&QA[gHi] = *(const bf16x8*)&PsB[row * 72 + ch * 8];
    *(bf16x8*)&QA[gHi + (size_t)32 * 1024] =
        *(const bf16x8*)&PsB[(row + 32) * 72 + ch * 8];
  }
}

// ---------------------------------------------------------------------------
// Output GEMM: out[m][n] = sum_k AO[m][k]*Wo[n][k], fp32 out, full-line f32x4.
// ---------------------------------------------------------------------------
__global__ __launch_bounds__(256) void gemm_out(
    const __bf16* __restrict__ AO, const __bf16* __restrict__ Wob,
    float* __restrict__ Of)
{
  __shared__ __bf16 As[128 * 32];
  __shared__ __bf16 Bs[128 * 32];
  __shared__ float  EsF[4 * 16 * 68];

  const int tid  = threadIdx.x;
  const int lane = tid & 63;
  const int wid  = tid >> 6;
  const int quad = lane >> 4;
  const int l16  = lane & 15;
  const int wm   = (wid >> 1) * 64;
  const int wn   = (wid & 1) * 64;
  const int lin = blockIdx.x;           // 256 blocks
  const int n0  = (lin & 7) * 128;
  const int m0  = (lin >> 3) * 128;

  const int r0 = tid >> 2, c0 = tid & 3;
  const int r1 = (tid + 256) >> 2;

  f32x4 acc[4][4];
  for (int i = 0; i < 4; ++i)
    for (int j = 0; j < 4; ++j) acc[i][j] = zero4();

  for (int k0 = 0; k0 < 1024; k0 += 32) {
    __syncthreads();
    GLDS16(AO  + (size_t)(m0 + r0) * 1024 + k0 + c0 * 8, &As[(size_t)tid * 8]);
    GLDS16(AO  + (size_t)(m0 + r1) * 1024 + k0 + c0 * 8, &As[(size_t)(tid + 256) * 8]);
    GLDS16(Wob + (size_t)(n0 + r0) * 1024 + k0 + c0 * 8, &Bs[(size_t)tid * 8]);
    GLDS16(Wob + (size_t)(n0 + r1) * 1024 + k0 + c0 * 8, &Bs[(size_t)(tid + 256) * 8]);
    __syncthreads();

    bf16x8 af[4], bfr[4];
    for (int i = 0; i < 4; ++i)
      af[i] = *(const bf16x8*)&As[(wm + i * 16 + l16) * 32 + quad * 8];
    for (int i = 0; i < 4; ++i)
      bfr[i] = *(const bf16x8*)&Bs[(wn + i * 16 + l16) * 32 + quad * 8];
    for (int mt = 0; mt < 4; ++mt)
      for (int nt = 0; nt < 4; ++nt)
        acc[mt][nt] = __builtin_amdgcn_mfma_f32_16x16x32_bf16(
            af[mt], bfr[nt], acc[mt][nt], 0, 0, 0);
  }

  float* es = &EsF[wid * 1088];         // 16 x 68 f32, per-wave private
  const int rl = lane >> 4, ch = lane & 15;
  for (int mt = 0; mt < 4; ++mt) {
    for (int nt = 0; nt < 4; ++nt)
      for (int r = 0; r < 4; ++r)
        es[(4 * quad + r) * 68 + nt * 16 + l16] = acc[mt][nt][r];
    size_t g0 = (size_t)(m0 + wm + mt * 16 + rl) * 1024 + n0 + wn + ch * 4;
    *(f32x4*)&Of[g0]             = *(const f32x4*)&es[rl * 68 + ch * 4];
    *(f32x4*)&Of[g0 + 4 * 1024]  = *(const f32x4*)&es[(rl + 4) * 68 + ch * 4];
    *(f32x4*)&Of[g0 + 8 * 1024]  = *(const f32x4*)&es[(rl + 8) * 68 + ch * 4];
    *(f32x4*)&Of[g0 + 12 * 1024] = *(const f32x4*)&es[(rl + 12) * 68 + ch * 4];
  }
}

// copy 8 bf16/lane
__global__ __launch_bounds__(256) void copy_bf16x8(
    const __bf16* __restrict__ src, __bf16* __restrict__ dst)
{
  size_t i = ((size_t)blockIdx.x * 256 + threadIdx.x) * 8;
  *(bf16x8*)&dst[i] = *(const bf16x8*)&src[i];
}

// ---------------------------------------------------------------------------
extern "C" void kernel_launch(void* const* d_in, const int* in_sizes, int n_in,
                              void* d_out, int out_size, void* d_ws, size_t ws_size,
                              hipStream_t stream) {
  const float* x  = (const float*)d_in[0];
  const float* Wq = (const float*)d_in[1];
  const float* Wk = (const float*)d_in[2];
  const float* Wv = (const float*)d_in[3];
  const float* Wo = (const float*)d_in[4];
  float* out = (float*)d_out;

  const size_t NELT = (size_t)4194304;             // 4M elems (8 MiB bf16)
  __bf16* Qp = (__bf16*)d_ws;        // plain Q, becomes AO in-place
  __bf16* Kp = Qp + NELT;            // plain K, later holds Wo bf16
  __bf16* Vt = Kp + NELT;            // V^T [bh][d][t]
  __bf16* xb = (__bf16*)d_out;       // d_out[0:8MB) scratch: x bf16
  __bf16* Wb = xb + NELT;            // d_out[8:16MB): W* bf16

  prep<<<dim3(4096), 256, 0, stream>>>(x, Wq, Wk, Wv, Wo, xb, Wb);
  gemm_qkv<<<dim3(768), 256, 0, stream>>>(xb, Wb, Qp, Kp, Vt);
  attn_fwd<<<dim3(512), 256, 0, stream>>>(Qp, Kp, Vt);
  copy_bf16x8<<<dim3(512), 256, 0, stream>>>(Wb + 3 * NELT / 4, Kp);
  gemm_out<<<dim3(256), 256, 0, stream>>>(Qp, Kp, out);
}